// Round 2
// baseline (564.699 us; speedup 1.0000x reference)
//
#include <hip/hip_runtime.h>

typedef unsigned short u16;
typedef __bf16 bf16x8 __attribute__((ext_vector_type(8)));
typedef float f32x4 __attribute__((ext_vector_type(4)));

#define B_  4
#define T_  2048
#define C_  1024
#define NH_ 16
#define D_  64
#define M_  (B_*T_)          // 8192
#define N_QKV (3*C_)         // 3072

// RNE float -> bf16 bits
__device__ __forceinline__ u16 f2bf(float f) {
  union { float f; unsigned u; } c; c.f = f;
  unsigned u = c.u;
  unsigned r = (u + 0x7fffu + ((u >> 16) & 1u)) >> 16;
  return (u16)r;
}

// ---------------- elementwise fp32 -> bf16 ----------------
__global__ __launch_bounds__(256) void conv_bf16(const float* __restrict__ in,
                                                 u16* __restrict__ out, int n) {
  int i = (blockIdx.x * 256 + threadIdx.x) * 4;
  if (i < n) {
    float4 f = *reinterpret_cast<const float4*>(in + i);
    u16 o[4] = { f2bf(f.x), f2bf(f.y), f2bf(f.z), f2bf(f.w) };
    *reinterpret_cast<uint2*>(out + i) = *reinterpret_cast<uint2*>(o);
  }
}

// ---------------- transpose fp32 [K][N] -> bf16 [N][K] ----------------
__global__ __launch_bounds__(256) void transpose_bf16(const float* __restrict__ in,
                                                      u16* __restrict__ out,
                                                      int K, int N) {
  __shared__ float tile[32][33];
  int bi = blockIdx.y;           // K/32
  int bj = blockIdx.x;           // N/32
  int tx = threadIdx.x & 31;
  int ty = threadIdx.x >> 5;     // 0..7
#pragma unroll
  for (int i = 0; i < 4; ++i) {
    int row = ty + i * 8;
    tile[row][tx] = in[(bi * 32 + row) * N + bj * 32 + tx];
  }
  __syncthreads();
#pragma unroll
  for (int i = 0; i < 4; ++i) {
    int row = ty + i * 8;
    out[(bj * 32 + row) * K + bi * 32 + tx] = f2bf(tile[tx][row]);
  }
}

// ---------------- QKV GEMM: A[M,K] x Bt[N,K] -> scatter q/k bf16, v TRANSPOSED ----------------
// 128x128 block tile, BK=32, 4 waves (2x2), each wave 64x64 = 4x4 MFMA tiles.
// q,k written [b,h,t,d]; v written [b,h,d,t] so attention can load V^T frags directly.
__global__ __launch_bounds__(256) void gemm_qkv(const u16* __restrict__ A,
                                                const u16* __restrict__ Bt,
                                                const float* __restrict__ b_attn,
                                                const float* __restrict__ bQ,
                                                const float* __restrict__ bK,
                                                u16* __restrict__ qo,
                                                u16* __restrict__ ko,
                                                u16* __restrict__ vo) {
  const int K = C_;
  int bm = blockIdx.y, bn = blockIdx.x;
  int tid = threadIdx.x;
  int wid = tid >> 6, lane = tid & 63;
  int lm = lane & 15, lq = lane >> 4;
  int wm = (wid >> 1) * 64, wn = (wid & 1) * 64;

  __shared__ u16 As[128][40];
  __shared__ u16 Bs[128][40];

  f32x4 acc[4][4];
#pragma unroll
  for (int i = 0; i < 4; ++i)
#pragma unroll
    for (int j = 0; j < 4; ++j) acc[i][j] = (f32x4){0.f, 0.f, 0.f, 0.f};

  const u16* Ab = A + (bm * 128) * K;
  const u16* Bb = Bt + (bn * 128) * K;
  int sr = tid >> 1;
  int sc = (tid & 1) * 16;

  for (int k0 = 0; k0 < K; k0 += 32) {
    ulonglong2 va0 = *reinterpret_cast<const ulonglong2*>(Ab + sr * K + k0 + sc);
    ulonglong2 va1 = *reinterpret_cast<const ulonglong2*>(Ab + sr * K + k0 + sc + 8);
    ulonglong2 vb0 = *reinterpret_cast<const ulonglong2*>(Bb + sr * K + k0 + sc);
    ulonglong2 vb1 = *reinterpret_cast<const ulonglong2*>(Bb + sr * K + k0 + sc + 8);
    __syncthreads();
    *reinterpret_cast<ulonglong2*>(&As[sr][sc]) = va0;
    *reinterpret_cast<ulonglong2*>(&As[sr][sc + 8]) = va1;
    *reinterpret_cast<ulonglong2*>(&Bs[sr][sc]) = vb0;
    *reinterpret_cast<ulonglong2*>(&Bs[sr][sc + 8]) = vb1;
    __syncthreads();
    bf16x8 af[4], bf[4];
#pragma unroll
    for (int mt = 0; mt < 4; ++mt)
      af[mt] = *reinterpret_cast<const bf16x8*>(&As[wm + mt * 16 + lm][lq * 8]);
#pragma unroll
    for (int nt = 0; nt < 4; ++nt)
      bf[nt] = *reinterpret_cast<const bf16x8*>(&Bs[wn + nt * 16 + lm][lq * 8]);
#pragma unroll
    for (int mt = 0; mt < 4; ++mt)
#pragma unroll
      for (int nt = 0; nt < 4; ++nt)
        acc[mt][nt] = __builtin_amdgcn_mfma_f32_16x16x32_bf16(af[mt], bf[nt], acc[mt][nt], 0, 0, 0);
  }

  // epilogue: C/D layout col=lane&15, row=(lane>>4)*4+reg  [verified m89/m91]
#pragma unroll
  for (int mt = 0; mt < 4; ++mt) {
#pragma unroll
    for (int nt = 0; nt < 4; ++nt) {
#pragma unroll
      for (int r = 0; r < 4; ++r) {
        int m = bm * 128 + wm + mt * 16 + lq * 4 + r;
        int n = bn * 128 + wn + nt * 16 + lm;
        float val = acc[mt][nt][r] + b_attn[n];
        int sel = n >> 10;
        int c = n & 1023;          // h*64+d
        int h = c >> 6;
        int d = c & 63;
        int b = m >> 11;
        int t = m & 2047;
        if (sel == 0)      qo[(((b * NH_ + h) * T_) + t) * D_ + d] = f2bf(val + bQ[c]);
        else if (sel == 1) ko[(((b * NH_ + h) * T_) + t) * D_ + d] = f2bf(val + bK[c]);
        else               vo[(((b * NH_ + h) * D_) + d) * T_ + t] = f2bf(val);  // transposed
      }
    }
  }
}

// ---------------- Flash attention (barrier-free K-loop) ----------------
// block = 256 threads (4 waves); one block per (b,h, 128-row q-tile).
// wave w owns q-rows [w*32, w*32+32) = 2 m-tiles. No LDS staging of Q/K/V:
// fragments are loaded directly from global (L1/L2-resident tiles). Only a
// per-wave LDS buffer (Ps) for the P C-layout -> A-layout transform.
__global__ __launch_bounds__(256) void attn_kernel(const u16* __restrict__ q,
                                                   const u16* __restrict__ k,
                                                   const u16* __restrict__ vt,
                                                   u16* __restrict__ y) {
  int qt = blockIdx.x & 15;       // 16 q-tiles of 128 rows
  int bh = blockIdx.x >> 4;       // b*NH + h
  int b = bh >> 4, h = bh & 15;
  int tid = threadIdx.x, wid = tid >> 6, lane = tid & 63;
  int lm = lane & 15, lq = lane >> 4;

  __shared__ u16 Ps[4][32][72];   // per-wave P relayout buffer (stride 72: 16B-aligned rows)

  const u16* qb = q + ((size_t)bh * T_ + qt * 128 + wid * 32) * D_;
  const u16* kb = k + (size_t)bh * T_ * D_;
  const u16* vb = vt + (size_t)bh * D_ * T_;   // [d][t]

  // Q fragments: A[m][k] with m=lane&15, k=(lane>>4)*8+j   (once, registers)
  bf16x8 aq[2][2];
#pragma unroll
  for (int mt = 0; mt < 2; ++mt) {
    aq[mt][0] = *reinterpret_cast<const bf16x8*>(qb + (mt * 16 + lm) * D_ + lq * 8);
    aq[mt][1] = *reinterpret_cast<const bf16x8*>(qb + (mt * 16 + lm) * D_ + 32 + lq * 8);
  }

  f32x4 o[2][4];
#pragma unroll
  for (int mt = 0; mt < 2; ++mt)
#pragma unroll
    for (int nt = 0; nt < 4; ++nt) o[mt][nt] = (f32x4){0.f, 0.f, 0.f, 0.f};
  float m_prev[2][4], lsum[2][4];
#pragma unroll
  for (int mt = 0; mt < 2; ++mt)
#pragma unroll
    for (int r = 0; r < 4; ++r) { m_prev[mt][r] = -1e30f; lsum[mt][r] = 0.f; }

  const float scale = 0.125f;  // 1/sqrt(64)
  const int kmax = 2 * qt + 1;

  for (int kbi = 0; kbi <= kmax; ++kbi) {
    // K fragments straight from global: B[n=key][k=d]
    bf16x8 kf[4][2];
#pragma unroll
    for (int nt = 0; nt < 4; ++nt) {
      const u16* kp = kb + (kbi * 64 + nt * 16 + lm) * D_ + lq * 8;
      kf[nt][0] = *reinterpret_cast<const bf16x8*>(kp);
      kf[nt][1] = *reinterpret_cast<const bf16x8*>(kp + 32);
    }

    // S = Q K^T : 2 m-tiles x 4 n-tiles
    f32x4 s[2][4];
#pragma unroll
    for (int mt = 0; mt < 2; ++mt)
#pragma unroll
      for (int nt = 0; nt < 4; ++nt) {
        f32x4 z = (f32x4){0.f, 0.f, 0.f, 0.f};
        z = __builtin_amdgcn_mfma_f32_16x16x32_bf16(aq[mt][0], kf[nt][0], z, 0, 0, 0);
        z = __builtin_amdgcn_mfma_f32_16x16x32_bf16(aq[mt][1], kf[nt][1], z, 0, 0, 0);
        s[mt][nt] = z;
      }

    // V^T fragments (issued before softmax so L2 latency overlaps it)
    bf16x8 vf[4][2];
#pragma unroll
    for (int nt = 0; nt < 4; ++nt) {
      const u16* vp = vb + (nt * 16 + lm) * T_ + kbi * 64 + lq * 8;
      vf[nt][0] = *reinterpret_cast<const bf16x8*>(vp);
      vf[nt][1] = *reinterpret_cast<const bf16x8*>(vp + 32);
    }

    bool maskt = (kbi >= 2 * qt);   // wave-uniform: only last two tiles touch the diagonal
    // online softmax per q-row (row = lq*4+r within m-tile, replicated over lm)
#pragma unroll
    for (int mt = 0; mt < 2; ++mt) {
#pragma unroll
      for (int r = 0; r < 4; ++r) {
        float mval = -1e30f;
#pragma unroll
        for (int nt = 0; nt < 4; ++nt) {
          float sv = s[mt][nt][r] * scale;
          if (maskt) {
            int qg = qt * 128 + wid * 32 + mt * 16 + lq * 4 + r;
            int kg = kbi * 64 + nt * 16 + lm;
            if (kg > qg) sv = -1e30f;
          }
          s[mt][nt][r] = sv;
          mval = fmaxf(mval, sv);
        }
#pragma unroll
        for (int off = 1; off < 16; off <<= 1) mval = fmaxf(mval, __shfl_xor(mval, off));
        float mnew = fmaxf(m_prev[mt][r], mval);
        float alpha = __expf(m_prev[mt][r] - mnew);
        float rs = 0.f;
#pragma unroll
        for (int nt = 0; nt < 4; ++nt) {
          float p = __expf(s[mt][nt][r] - mnew);
          s[mt][nt][r] = p;
          rs += p;
        }
#pragma unroll
        for (int off = 1; off < 16; off <<= 1) rs += __shfl_xor(rs, off);
        lsum[mt][r] = lsum[mt][r] * alpha + rs;
        m_prev[mt][r] = mnew;
#pragma unroll
        for (int nt = 0; nt < 4; ++nt) o[mt][nt][r] *= alpha;
        // P: C-layout -> A-layout via per-wave LDS (verified m120 transform)
#pragma unroll
        for (int nt = 0; nt < 4; ++nt)
          Ps[wid][mt * 16 + lq * 4 + r][nt * 16 + lm] = f2bf(s[mt][nt][r]);
      }
    }

    // PV: O += P V   (per-wave LDS, no cross-wave sync needed)
#pragma unroll
    for (int mt = 0; mt < 2; ++mt) {
      bf16x8 p0 = *reinterpret_cast<const bf16x8*>(&Ps[wid][mt * 16 + lm][lq * 8]);
      bf16x8 p1 = *reinterpret_cast<const bf16x8*>(&Ps[wid][mt * 16 + lm][32 + lq * 8]);
#pragma unroll
      for (int nt = 0; nt < 4; ++nt) {
        o[mt][nt] = __builtin_amdgcn_mfma_f32_16x16x32_bf16(p0, vf[nt][0], o[mt][nt], 0, 0, 0);
        o[mt][nt] = __builtin_amdgcn_mfma_f32_16x16x32_bf16(p1, vf[nt][1], o[mt][nt], 0, 0, 0);
      }
    }
  }

  // write y as [B, T, NH, D] == [B,T,C]
#pragma unroll
  for (int mt = 0; mt < 2; ++mt) {
#pragma unroll
    for (int nt = 0; nt < 4; ++nt) {
#pragma unroll
      for (int r = 0; r < 4; ++r) {
        float val = o[mt][nt][r] / lsum[mt][r];
        int qg = qt * 128 + wid * 32 + mt * 16 + lq * 4 + r;
        int d = nt * 16 + lm;
        y[((size_t)(b * T_ + qg) * NH_ + h) * D_ + d] = f2bf(val);
      }
    }
  }
}

// ---------------- Proj GEMM: y[M,K] x WpT[N,K] + b_proj -> out fp32 ----------------
__global__ __launch_bounds__(256) void gemm_proj(const u16* __restrict__ A,
                                                 const u16* __restrict__ Bt,
                                                 const float* __restrict__ b_proj,
                                                 float* __restrict__ out) {
  const int K = C_, N = C_;
  int bm = blockIdx.y, bn = blockIdx.x;
  int tid = threadIdx.x;
  int wid = tid >> 6, lane = tid & 63;
  int lm = lane & 15, lq = lane >> 4;
  int wm = (wid >> 1) * 64, wn = (wid & 1) * 64;

  __shared__ u16 As[128][40];
  __shared__ u16 Bs[128][40];

  f32x4 acc[4][4];
#pragma unroll
  for (int i = 0; i < 4; ++i)
#pragma unroll
    for (int j = 0; j < 4; ++j) acc[i][j] = (f32x4){0.f, 0.f, 0.f, 0.f};

  const u16* Ab = A + (bm * 128) * K;
  const u16* Bb = Bt + (bn * 128) * K;
  int sr = tid >> 1;
  int sc = (tid & 1) * 16;

  for (int k0 = 0; k0 < K; k0 += 32) {
    ulonglong2 va0 = *reinterpret_cast<const ulonglong2*>(Ab + sr * K + k0 + sc);
    ulonglong2 va1 = *reinterpret_cast<const ulonglong2*>(Ab + sr * K + k0 + sc + 8);
    ulonglong2 vb0 = *reinterpret_cast<const ulonglong2*>(Bb + sr * K + k0 + sc);
    ulonglong2 vb1 = *reinterpret_cast<const ulonglong2*>(Bb + sr * K + k0 + sc + 8);
    __syncthreads();
    *reinterpret_cast<ulonglong2*>(&As[sr][sc]) = va0;
    *reinterpret_cast<ulonglong2*>(&As[sr][sc + 8]) = va1;
    *reinterpret_cast<ulonglong2*>(&Bs[sr][sc]) = vb0;
    *reinterpret_cast<ulonglong2*>(&Bs[sr][sc + 8]) = vb1;
    __syncthreads();
    bf16x8 af[4], bf[4];
#pragma unroll
    for (int mt = 0; mt < 4; ++mt)
      af[mt] = *reinterpret_cast<const bf16x8*>(&As[wm + mt * 16 + lm][lq * 8]);
#pragma unroll
    for (int nt = 0; nt < 4; ++nt)
      bf[nt] = *reinterpret_cast<const bf16x8*>(&Bs[wn + nt * 16 + lm][lq * 8]);
#pragma unroll
    for (int mt = 0; mt < 4; ++mt)
#pragma unroll
      for (int nt = 0; nt < 4; ++nt)
        acc[mt][nt] = __builtin_amdgcn_mfma_f32_16x16x32_bf16(af[mt], bf[nt], acc[mt][nt], 0, 0, 0);
  }

#pragma unroll
  for (int mt = 0; mt < 4; ++mt) {
#pragma unroll
    for (int nt = 0; nt < 4; ++nt) {
#pragma unroll
      for (int r = 0; r < 4; ++r) {
        int m = bm * 128 + wm + mt * 16 + lq * 4 + r;
        int n = bn * 128 + wn + nt * 16 + lm;
        out[m * N + n] = acc[mt][nt][r] + b_proj[n];
      }
    }
  }
}

extern "C" void kernel_launch(void* const* d_in, const int* in_sizes, int n_in,
                              void* d_out, int out_size, void* d_ws, size_t ws_size,
                              hipStream_t stream) {
  const float* x      = (const float*)d_in[0];
  const float* W_attn = (const float*)d_in[1];
  const float* b_attn = (const float*)d_in[2];
  const float* bQ     = (const float*)d_in[3];
  const float* bK     = (const float*)d_in[4];
  const float* W_proj = (const float*)d_in[5];
  const float* b_proj = (const float*)d_in[6];
  float* out = (float*)d_out;

  char* ws = (char*)d_ws;
  u16* xb  = (u16*)(ws);                              // [8192][1024]      16 MB
  u16* WaT = (u16*)(ws + 16777216);                   // [3072][1024]       6 MB
  u16* WpT = (u16*)(ws + 23068672);                   // [1024][1024]       2 MB
  u16* qw  = (u16*)(ws + 25165824);                   // [B,NH,T,D]        16 MB
  u16* kw  = (u16*)(ws + 41943040);                   // [B,NH,T,D]        16 MB
  u16* vw  = (u16*)(ws + 58720256);                   // [B,NH,D,T] (V^T)  16 MB
  u16* yw  = (u16*)(ws + 75497472);                   // [8192][1024]      16 MB

  conv_bf16<<<M_ * C_ / (4 * 256), 256, 0, stream>>>(x, xb, M_ * C_);
  {
    dim3 g(N_QKV / 32, C_ / 32);
    transpose_bf16<<<g, 256, 0, stream>>>(W_attn, WaT, C_, N_QKV);
  }
  {
    dim3 g(C_ / 32, C_ / 32);
    transpose_bf16<<<g, 256, 0, stream>>>(W_proj, WpT, C_, C_);
  }
  {
    dim3 g(N_QKV / 128, M_ / 128);  // (24, 64)
    gemm_qkv<<<g, 256, 0, stream>>>(xb, WaT, b_attn, bQ, bK, qw, kw, vw);
  }
  attn_kernel<<<B_ * NH_ * (T_ / 128), 256, 0, stream>>>(qw, kw, vw, yw);
  {
    dim3 g(C_ / 128, M_ / 128);     // (8, 64)
    gemm_proj<<<g, 256, 0, stream>>>(yw, WpT, b_proj, out);
  }
}

// Round 3
// 461.811 us; speedup vs baseline: 1.2228x; 1.2228x over previous
//
#include <hip/hip_runtime.h>

typedef unsigned short u16;
typedef __bf16 bf16x8 __attribute__((ext_vector_type(8)));
typedef float f32x4 __attribute__((ext_vector_type(4)));

#define B_  4
#define T_  2048
#define C_  1024
#define NH_ 16
#define D_  64
#define M_  (B_*T_)          // 8192
#define N_QKV (3*C_)         // 3072

// RNE float -> bf16 bits
__device__ __forceinline__ u16 f2bf(float f) {
  union { float f; unsigned u; } c; c.f = f;
  unsigned u = c.u;
  unsigned r = (u + 0x7fffu + ((u >> 16) & 1u)) >> 16;
  return (u16)r;
}

// ---------------- elementwise fp32 -> bf16 ----------------
__global__ __launch_bounds__(256) void conv_bf16(const float* __restrict__ in,
                                                 u16* __restrict__ out, int n) {
  int i = (blockIdx.x * 256 + threadIdx.x) * 4;
  if (i < n) {
    float4 f = *reinterpret_cast<const float4*>(in + i);
    u16 o[4] = { f2bf(f.x), f2bf(f.y), f2bf(f.z), f2bf(f.w) };
    *reinterpret_cast<uint2*>(out + i) = *reinterpret_cast<uint2*>(o);
  }
}

// ---------------- transpose fp32 [K][N] -> bf16 [N][K] ----------------
__global__ __launch_bounds__(256) void transpose_bf16(const float* __restrict__ in,
                                                      u16* __restrict__ out,
                                                      int K, int N) {
  __shared__ float tile[32][33];
  int bi = blockIdx.y;           // K/32
  int bj = blockIdx.x;           // N/32
  int tx = threadIdx.x & 31;
  int ty = threadIdx.x >> 5;     // 0..7
#pragma unroll
  for (int i = 0; i < 4; ++i) {
    int row = ty + i * 8;
    tile[row][tx] = in[(bi * 32 + row) * N + bj * 32 + tx];
  }
  __syncthreads();
#pragma unroll
  for (int i = 0; i < 4; ++i) {
    int row = ty + i * 8;
    out[(bj * 32 + row) * K + bi * 32 + tx] = f2bf(tile[tx][row]);
  }
}

// ---------------- QKV GEMM: A[M,K] x Bt[N,K] -> scatter q/k bf16, v TRANSPOSED ----------------
__global__ __launch_bounds__(256) void gemm_qkv(const u16* __restrict__ A,
                                                const u16* __restrict__ Bt,
                                                const float* __restrict__ b_attn,
                                                const float* __restrict__ bQ,
                                                const float* __restrict__ bK,
                                                u16* __restrict__ qo,
                                                u16* __restrict__ ko,
                                                u16* __restrict__ vo) {
  const int K = C_;
  int bm = blockIdx.y, bn = blockIdx.x;
  int tid = threadIdx.x;
  int wid = tid >> 6, lane = tid & 63;
  int lm = lane & 15, lq = lane >> 4;
  int wm = (wid >> 1) * 64, wn = (wid & 1) * 64;

  __shared__ u16 As[128][40];
  __shared__ u16 Bs[128][40];

  f32x4 acc[4][4];
#pragma unroll
  for (int i = 0; i < 4; ++i)
#pragma unroll
    for (int j = 0; j < 4; ++j) acc[i][j] = (f32x4){0.f, 0.f, 0.f, 0.f};

  const u16* Ab = A + (bm * 128) * K;
  const u16* Bb = Bt + (bn * 128) * K;
  int sr = tid >> 1;
  int sc = (tid & 1) * 16;

  for (int k0 = 0; k0 < K; k0 += 32) {
    ulonglong2 va0 = *reinterpret_cast<const ulonglong2*>(Ab + sr * K + k0 + sc);
    ulonglong2 va1 = *reinterpret_cast<const ulonglong2*>(Ab + sr * K + k0 + sc + 8);
    ulonglong2 vb0 = *reinterpret_cast<const ulonglong2*>(Bb + sr * K + k0 + sc);
    ulonglong2 vb1 = *reinterpret_cast<const ulonglong2*>(Bb + sr * K + k0 + sc + 8);
    __syncthreads();
    *reinterpret_cast<ulonglong2*>(&As[sr][sc]) = va0;
    *reinterpret_cast<ulonglong2*>(&As[sr][sc + 8]) = va1;
    *reinterpret_cast<ulonglong2*>(&Bs[sr][sc]) = vb0;
    *reinterpret_cast<ulonglong2*>(&Bs[sr][sc + 8]) = vb1;
    __syncthreads();
    bf16x8 af[4], bf[4];
#pragma unroll
    for (int mt = 0; mt < 4; ++mt)
      af[mt] = *reinterpret_cast<const bf16x8*>(&As[wm + mt * 16 + lm][lq * 8]);
#pragma unroll
    for (int nt = 0; nt < 4; ++nt)
      bf[nt] = *reinterpret_cast<const bf16x8*>(&Bs[wn + nt * 16 + lm][lq * 8]);
#pragma unroll
    for (int mt = 0; mt < 4; ++mt)
#pragma unroll
      for (int nt = 0; nt < 4; ++nt)
        acc[mt][nt] = __builtin_amdgcn_mfma_f32_16x16x32_bf16(af[mt], bf[nt], acc[mt][nt], 0, 0, 0);
  }

  // epilogue: C/D layout col=lane&15, row=(lane>>4)*4+reg  [verified m89/m91]
#pragma unroll
  for (int mt = 0; mt < 4; ++mt) {
#pragma unroll
    for (int nt = 0; nt < 4; ++nt) {
#pragma unroll
      for (int r = 0; r < 4; ++r) {
        int m = bm * 128 + wm + mt * 16 + lq * 4 + r;
        int n = bn * 128 + wn + nt * 16 + lm;
        float val = acc[mt][nt][r] + b_attn[n];
        int sel = n >> 10;
        int c = n & 1023;          // h*64+d
        int h = c >> 6;
        int d = c & 63;
        int b = m >> 11;
        int t = m & 2047;
        if (sel == 0)      qo[(((b * NH_ + h) * T_) + t) * D_ + d] = f2bf(val + bQ[c]);
        else if (sel == 1) ko[(((b * NH_ + h) * T_) + t) * D_ + d] = f2bf(val + bK[c]);
        else               vo[(((b * NH_ + h) * D_) + d) * T_ + t] = f2bf(val);  // transposed
      }
    }
  }
}

// ---------------- Flash attention, S^T formulation, single-wave blocks ----------------
// One wave (64 threads) per (b, h, 32-row q-tile). Computes S^T = K Q^T so the
// C-layout puts q in the lane dim (col=lm): softmax reduces over regs + 2 shfl;
// state (m,l) is a per-lane scalar. PV as O^T = V^T P^T (A-frag = pre-transposed
// V loaded straight from global). P relayout: 8x ds_write_b64 + 4x ds_read_b128
// per iteration, same-wave (no barriers anywhere in the loop).
__global__ __launch_bounds__(64) void attn_kernel(const u16* __restrict__ q,
                                                  const u16* __restrict__ k,
                                                  const u16* __restrict__ vt,
                                                  u16* __restrict__ y) {
  int bid = blockIdx.x;
  int qt = 63 - (bid & 63);        // reversed: longest q-tiles dispatch first
  int bh = bid >> 6;
  int b = bh >> 4, h = bh & 15;
  int lane = threadIdx.x;
  int lm = lane & 15, lq = lane >> 4;

  __shared__ u16 Ps[2][16][72];    // [q-subtile][q-row][local key], row stride 72

  const u16* qb = q + ((size_t)bh * T_ + qt * 32) * D_;
  const u16* kb = k + (size_t)bh * T_ * D_;
  const u16* vb = vt + (size_t)bh * D_ * T_;   // [d][t]

  // Q as B-operand: lane n=q=lm, k=d=lq*8+j
  bf16x8 bq[2][2];
#pragma unroll
  for (int qt2 = 0; qt2 < 2; ++qt2) {
    const u16* qp = qb + (qt2 * 16 + lm) * D_ + lq * 8;
    bq[qt2][0] = *reinterpret_cast<const bf16x8*>(qp);
    bq[qt2][1] = *reinterpret_cast<const bf16x8*>(qp + 32);
  }

  f32x4 o[4][2];                   // O^T tiles: [d-tile][q-subtile]
#pragma unroll
  for (int dt = 0; dt < 4; ++dt)
#pragma unroll
    for (int qt2 = 0; qt2 < 2; ++qt2) o[dt][qt2] = (f32x4){0.f, 0.f, 0.f, 0.f};
  float mprev[2] = {-1e30f, -1e30f}, lsum[2] = {0.f, 0.f};

  const float sc = 0.125f * 1.44269504088896f;   // 1/sqrt(D) * log2(e)
  const int klast = qt >> 1;

  for (int kbi = 0; kbi <= klast; ++kbi) {
    // K as A-operand: lane m=key=lm, k=d
    bf16x8 kf[4][2];
#pragma unroll
    for (int nt = 0; nt < 4; ++nt) {
      const u16* kp = kb + (size_t)(kbi * 64 + nt * 16 + lm) * D_ + lq * 8;
      kf[nt][0] = *reinterpret_cast<const bf16x8*>(kp);
      kf[nt][1] = *reinterpret_cast<const bf16x8*>(kp + 32);
    }
    // V^T as A-operand: lane m=d=lm(+16*dt), k=key
    bf16x8 vf[4][2];
#pragma unroll
    for (int dt = 0; dt < 4; ++dt) {
      const u16* vp = vb + (size_t)(dt * 16 + lm) * T_ + kbi * 64 + lq * 8;
      vf[dt][0] = *reinterpret_cast<const bf16x8*>(vp);
      vf[dt][1] = *reinterpret_cast<const bf16x8*>(vp + 32);
    }

    // S^T[key][q]: rows=key (lq*4+r), cols=q (lm)
    f32x4 s[4][2];
#pragma unroll
    for (int kt = 0; kt < 4; ++kt)
#pragma unroll
      for (int qt2 = 0; qt2 < 2; ++qt2) {
        f32x4 z = (f32x4){0.f, 0.f, 0.f, 0.f};
        z = __builtin_amdgcn_mfma_f32_16x16x32_bf16(kf[kt][0], bq[qt2][0], z, 0, 0, 0);
        z = __builtin_amdgcn_mfma_f32_16x16x32_bf16(kf[kt][1], bq[qt2][1], z, 0, 0, 0);
        s[kt][qt2] = z;
      }

    bool maskt = (kbi == klast);
#pragma unroll
    for (int qt2 = 0; qt2 < 2; ++qt2) {
      int qg = qt * 32 + qt2 * 16 + lm;
      float mval = -1e30f;
#pragma unroll
      for (int kt = 0; kt < 4; ++kt)
#pragma unroll
        for (int r = 0; r < 4; ++r) {
          float sv = s[kt][qt2][r] * sc;
          if (maskt) {
            int key = kbi * 64 + kt * 16 + lq * 4 + r;
            if (key > qg) sv = -1e30f;
          }
          s[kt][qt2][r] = sv;
          mval = fmaxf(mval, sv);
        }
      mval = fmaxf(mval, __shfl_xor(mval, 16));
      mval = fmaxf(mval, __shfl_xor(mval, 32));
      float mnew = fmaxf(mprev[qt2], mval);
      float alpha = __builtin_exp2f(mprev[qt2] - mnew);
      float rs = 0.f;
#pragma unroll
      for (int kt = 0; kt < 4; ++kt) {
        u16 pk[4];
#pragma unroll
        for (int r = 0; r < 4; ++r) {
          float p = __builtin_exp2f(s[kt][qt2][r] - mnew);
          rs += p;
          pk[r] = f2bf(p);
        }
        *reinterpret_cast<unsigned long long*>(&Ps[qt2][lm][kt * 16 + lq * 4]) =
            *reinterpret_cast<unsigned long long*>(pk);
      }
      rs += __shfl_xor(rs, 16);
      rs += __shfl_xor(rs, 32);
      lsum[qt2] = lsum[qt2] * alpha + rs;
      mprev[qt2] = mnew;
#pragma unroll
      for (int dt = 0; dt < 4; ++dt) o[dt][qt2] *= alpha;
    }

    // PV: O^T += V^T P^T  (B-frag of P read back per-wave, no barrier)
#pragma unroll
    for (int qt2 = 0; qt2 < 2; ++qt2) {
      bf16x8 p0 = *reinterpret_cast<const bf16x8*>(&Ps[qt2][lm][lq * 8]);
      bf16x8 p1 = *reinterpret_cast<const bf16x8*>(&Ps[qt2][lm][32 + lq * 8]);
#pragma unroll
      for (int dt = 0; dt < 4; ++dt) {
        o[dt][qt2] = __builtin_amdgcn_mfma_f32_16x16x32_bf16(vf[dt][0], p0, o[dt][qt2], 0, 0, 0);
        o[dt][qt2] = __builtin_amdgcn_mfma_f32_16x16x32_bf16(vf[dt][1], p1, o[dt][qt2], 0, 0, 0);
      }
    }
  }

  // write y[b][t=q][h][d]; O^T C-layout: col=q=lm, row=d=dt*16+lq*4+r -> 8B stores
#pragma unroll
  for (int qt2 = 0; qt2 < 2; ++qt2) {
    float inv = 1.f / lsum[qt2];
    int qg = qt * 32 + qt2 * 16 + lm;
#pragma unroll
    for (int dt = 0; dt < 4; ++dt) {
      u16 w[4];
#pragma unroll
      for (int r = 0; r < 4; ++r) w[r] = f2bf(o[dt][qt2][r] * inv);
      int d = dt * 16 + lq * 4;
      *reinterpret_cast<uint2*>(&y[((size_t)(b * T_ + qg) * NH_ + h) * D_ + d]) =
          *reinterpret_cast<uint2*>(w);
    }
  }
}

// ---------------- Proj GEMM: y[M,K] x WpT[N,K] + b_proj -> out fp32 ----------------
__global__ __launch_bounds__(256) void gemm_proj(const u16* __restrict__ A,
                                                 const u16* __restrict__ Bt,
                                                 const float* __restrict__ b_proj,
                                                 float* __restrict__ out) {
  const int K = C_, N = C_;
  int bm = blockIdx.y, bn = blockIdx.x;
  int tid = threadIdx.x;
  int wid = tid >> 6, lane = tid & 63;
  int lm = lane & 15, lq = lane >> 4;
  int wm = (wid >> 1) * 64, wn = (wid & 1) * 64;

  __shared__ u16 As[128][40];
  __shared__ u16 Bs[128][40];

  f32x4 acc[4][4];
#pragma unroll
  for (int i = 0; i < 4; ++i)
#pragma unroll
    for (int j = 0; j < 4; ++j) acc[i][j] = (f32x4){0.f, 0.f, 0.f, 0.f};

  const u16* Ab = A + (bm * 128) * K;
  const u16* Bb = Bt + (bn * 128) * K;
  int sr = tid >> 1;
  int sc = (tid & 1) * 16;

  for (int k0 = 0; k0 < K; k0 += 32) {
    ulonglong2 va0 = *reinterpret_cast<const ulonglong2*>(Ab + sr * K + k0 + sc);
    ulonglong2 va1 = *reinterpret_cast<const ulonglong2*>(Ab + sr * K + k0 + sc + 8);
    ulonglong2 vb0 = *reinterpret_cast<const ulonglong2*>(Bb + sr * K + k0 + sc);
    ulonglong2 vb1 = *reinterpret_cast<const ulonglong2*>(Bb + sr * K + k0 + sc + 8);
    __syncthreads();
    *reinterpret_cast<ulonglong2*>(&As[sr][sc]) = va0;
    *reinterpret_cast<ulonglong2*>(&As[sr][sc + 8]) = va1;
    *reinterpret_cast<ulonglong2*>(&Bs[sr][sc]) = vb0;
    *reinterpret_cast<ulonglong2*>(&Bs[sr][sc + 8]) = vb1;
    __syncthreads();
    bf16x8 af[4], bf[4];
#pragma unroll
    for (int mt = 0; mt < 4; ++mt)
      af[mt] = *reinterpret_cast<const bf16x8*>(&As[wm + mt * 16 + lm][lq * 8]);
#pragma unroll
    for (int nt = 0; nt < 4; ++nt)
      bf[nt] = *reinterpret_cast<const bf16x8*>(&Bs[wn + nt * 16 + lm][lq * 8]);
#pragma unroll
    for (int mt = 0; mt < 4; ++mt)
#pragma unroll
      for (int nt = 0; nt < 4; ++nt)
        acc[mt][nt] = __builtin_amdgcn_mfma_f32_16x16x32_bf16(af[mt], bf[nt], acc[mt][nt], 0, 0, 0);
  }

#pragma unroll
  for (int mt = 0; mt < 4; ++mt) {
#pragma unroll
    for (int nt = 0; nt < 4; ++nt) {
#pragma unroll
      for (int r = 0; r < 4; ++r) {
        int m = bm * 128 + wm + mt * 16 + lq * 4 + r;
        int n = bn * 128 + wn + nt * 16 + lm;
        out[m * N + n] = acc[mt][nt][r] + b_proj[n];
      }
    }
  }
}

extern "C" void kernel_launch(void* const* d_in, const int* in_sizes, int n_in,
                              void* d_out, int out_size, void* d_ws, size_t ws_size,
                              hipStream_t stream) {
  const float* x      = (const float*)d_in[0];
  const float* W_attn = (const float*)d_in[1];
  const float* b_attn = (const float*)d_in[2];
  const float* bQ     = (const float*)d_in[3];
  const float* bK     = (const float*)d_in[4];
  const float* W_proj = (const float*)d_in[5];
  const float* b_proj = (const float*)d_in[6];
  float* out = (float*)d_out;

  char* ws = (char*)d_ws;
  u16* xb  = (u16*)(ws);                              // [8192][1024]      16 MB
  u16* WaT = (u16*)(ws + 16777216);                   // [3072][1024]       6 MB
  u16* WpT = (u16*)(ws + 23068672);                   // [1024][1024]       2 MB
  u16* qw  = (u16*)(ws + 25165824);                   // [B,NH,T,D]        16 MB
  u16* kw  = (u16*)(ws + 41943040);                   // [B,NH,T,D]        16 MB
  u16* vw  = (u16*)(ws + 58720256);                   // [B,NH,D,T] (V^T)  16 MB
  u16* yw  = (u16*)(ws + 75497472);                   // [8192][1024]      16 MB

  conv_bf16<<<M_ * C_ / (4 * 256), 256, 0, stream>>>(x, xb, M_ * C_);
  {
    dim3 g(N_QKV / 32, C_ / 32);
    transpose_bf16<<<g, 256, 0, stream>>>(W_attn, WaT, C_, N_QKV);
  }
  {
    dim3 g(C_ / 32, C_ / 32);
    transpose_bf16<<<g, 256, 0, stream>>>(W_proj, WpT, C_, C_);
  }
  {
    dim3 g(N_QKV / 128, M_ / 128);  // (24, 64)
    gemm_qkv<<<g, 256, 0, stream>>>(xb, WaT, b_attn, bQ, bK, qw, kw, vw);
  }
  attn_kernel<<<B_ * NH_ * (T_ / 32), 64, 0, stream>>>(qw, kw, vw, yw);
  {
    dim3 g(C_ / 128, M_ / 128);     // (8, 64)
    gemm_proj<<<g, 256, 0, stream>>>(yw, WpT, b_proj, out);
  }
}

// Round 4
// 401.238 us; speedup vs baseline: 1.4074x; 1.1510x over previous
//
#include <hip/hip_runtime.h>

typedef unsigned short u16;
typedef __bf16 bf16x8 __attribute__((ext_vector_type(8)));
typedef float f32x4 __attribute__((ext_vector_type(4)));

#define B_  4
#define T_  2048
#define C_  1024
#define NH_ 16
#define D_  64
#define M_  (B_*T_)          // 8192
#define N_QKV (3*C_)         // 3072

#define ATTN_WAVES 2048      // 8 per CU
#define ATTN_ITEMS 4096      // 64 bh x 64 q-tiles of 32 rows

// RNE float -> bf16 bits
__device__ __forceinline__ u16 f2bf(float f) {
  union { float f; unsigned u; } c; c.f = f;
  unsigned u = c.u;
  unsigned r = (u + 0x7fffu + ((u >> 16) & 1u)) >> 16;
  return (u16)r;
}

// ---------------- elementwise fp32 -> bf16 ----------------
__global__ __launch_bounds__(256) void conv_bf16(const float* __restrict__ in,
                                                 u16* __restrict__ out, int n) {
  int i = (blockIdx.x * 256 + threadIdx.x) * 4;
  if (i < n) {
    float4 f = *reinterpret_cast<const float4*>(in + i);
    u16 o[4] = { f2bf(f.x), f2bf(f.y), f2bf(f.z), f2bf(f.w) };
    *reinterpret_cast<uint2*>(out + i) = *reinterpret_cast<uint2*>(o);
  }
}

// ---------------- transpose fp32 [K][N] -> bf16 [N][K] ----------------
__global__ __launch_bounds__(256) void transpose_bf16(const float* __restrict__ in,
                                                      u16* __restrict__ out,
                                                      int K, int N) {
  __shared__ float tile[32][33];
  int bi = blockIdx.y;           // K/32
  int bj = blockIdx.x;           // N/32
  int tx = threadIdx.x & 31;
  int ty = threadIdx.x >> 5;     // 0..7
#pragma unroll
  for (int i = 0; i < 4; ++i) {
    int row = ty + i * 8;
    tile[row][tx] = in[(bi * 32 + row) * N + bj * 32 + tx];
  }
  __syncthreads();
#pragma unroll
  for (int i = 0; i < 4; ++i) {
    int row = ty + i * 8;
    out[(bj * 32 + row) * K + bi * 32 + tx] = f2bf(tile[tx][row]);
  }
}

// ---------------- QKV GEMM: A[M,K] x Bt[N,K] -> scatter q/k bf16, v TRANSPOSED ----------------
// q is stored PRE-SCALED by 1/sqrt(D)*log2(e) so attention softmax works in
// exp2 domain with no per-score multiply. Also zero-inits the attention
// work-stealing counter (stream order guarantees visibility).
__global__ __launch_bounds__(256) void gemm_qkv(const u16* __restrict__ A,
                                                const u16* __restrict__ Bt,
                                                const float* __restrict__ b_attn,
                                                const float* __restrict__ bQ,
                                                const float* __restrict__ bK,
                                                u16* __restrict__ qo,
                                                u16* __restrict__ ko,
                                                u16* __restrict__ vo,
                                                unsigned* __restrict__ ctr) {
  const int K = C_;
  int bm = blockIdx.y, bn = blockIdx.x;
  int tid = threadIdx.x;
  if (tid == 0 && bm == 0 && bn == 0) *ctr = ATTN_WAVES;  // stealing starts past static items
  int wid = tid >> 6, lane = tid & 63;
  int lm = lane & 15, lq = lane >> 4;
  int wm = (wid >> 1) * 64, wn = (wid & 1) * 64;

  __shared__ u16 As[128][40];
  __shared__ u16 Bs[128][40];

  f32x4 acc[4][4];
#pragma unroll
  for (int i = 0; i < 4; ++i)
#pragma unroll
    for (int j = 0; j < 4; ++j) acc[i][j] = (f32x4){0.f, 0.f, 0.f, 0.f};

  const u16* Ab = A + (bm * 128) * K;
  const u16* Bb = Bt + (bn * 128) * K;
  int sr = tid >> 1;
  int sc = (tid & 1) * 16;

  for (int k0 = 0; k0 < K; k0 += 32) {
    ulonglong2 va0 = *reinterpret_cast<const ulonglong2*>(Ab + sr * K + k0 + sc);
    ulonglong2 va1 = *reinterpret_cast<const ulonglong2*>(Ab + sr * K + k0 + sc + 8);
    ulonglong2 vb0 = *reinterpret_cast<const ulonglong2*>(Bb + sr * K + k0 + sc);
    ulonglong2 vb1 = *reinterpret_cast<const ulonglong2*>(Bb + sr * K + k0 + sc + 8);
    __syncthreads();
    *reinterpret_cast<ulonglong2*>(&As[sr][sc]) = va0;
    *reinterpret_cast<ulonglong2*>(&As[sr][sc + 8]) = va1;
    *reinterpret_cast<ulonglong2*>(&Bs[sr][sc]) = vb0;
    *reinterpret_cast<ulonglong2*>(&Bs[sr][sc + 8]) = vb1;
    __syncthreads();
    bf16x8 af[4], bf[4];
#pragma unroll
    for (int mt = 0; mt < 4; ++mt)
      af[mt] = *reinterpret_cast<const bf16x8*>(&As[wm + mt * 16 + lm][lq * 8]);
#pragma unroll
    for (int nt = 0; nt < 4; ++nt)
      bf[nt] = *reinterpret_cast<const bf16x8*>(&Bs[wn + nt * 16 + lm][lq * 8]);
#pragma unroll
    for (int mt = 0; mt < 4; ++mt)
#pragma unroll
      for (int nt = 0; nt < 4; ++nt)
        acc[mt][nt] = __builtin_amdgcn_mfma_f32_16x16x32_bf16(af[mt], bf[nt], acc[mt][nt], 0, 0, 0);
  }

  const float qscale = 0.18033688011112042f;  // 1/sqrt(64) * log2(e)
  // epilogue: C/D layout col=lane&15, row=(lane>>4)*4+reg  [verified m89/m91]
#pragma unroll
  for (int mt = 0; mt < 4; ++mt) {
#pragma unroll
    for (int nt = 0; nt < 4; ++nt) {
#pragma unroll
      for (int r = 0; r < 4; ++r) {
        int m = bm * 128 + wm + mt * 16 + lq * 4 + r;
        int n = bn * 128 + wn + nt * 16 + lm;
        float val = acc[mt][nt][r] + b_attn[n];
        int sel = n >> 10;
        int c = n & 1023;          // h*64+d
        int h = c >> 6;
        int d = c & 63;
        int b = m >> 11;
        int t = m & 2047;
        if (sel == 0)      qo[(((b * NH_ + h) * T_) + t) * D_ + d] = f2bf((val + bQ[c]) * qscale);
        else if (sel == 1) ko[(((b * NH_ + h) * T_) + t) * D_ + d] = f2bf(val + bK[c]);
        else               vo[(((b * NH_ + h) * D_) + d) * T_ + t] = f2bf(val);  // transposed
      }
    }
  }
}

// ---------------- Flash attention: persistent waves + work stealing ----------------
// 2048 single-wave blocks. Work item idx in [0,4096): qt = 63-(idx>>6) (longest
// first), bh = idx&63. Wave processes item blockIdx.x, then steals from *ctr.
// S^T = K Q^T formulation (q in lane dim): softmax state per-lane scalar,
// 4 shfl per 64-key iter; P relayout via per-wave LDS, truncating bf16 pack.
__global__ __launch_bounds__(64) void attn_kernel(const u16* __restrict__ q,
                                                  const u16* __restrict__ k,
                                                  const u16* __restrict__ vt,
                                                  u16* __restrict__ y,
                                                  unsigned* __restrict__ ctr) {
  int lane = threadIdx.x;
  int lm = lane & 15, lq = lane >> 4;

  __shared__ u16 Ps[2][16][72];    // [q-subtile][q-row][local key], row stride 72

  int idx = blockIdx.x;
  while (idx < ATTN_ITEMS) {
    int qt = 63 - (idx >> 6);
    int bh = idx & 63;
    int b = bh >> 4, h = bh & 15;

    const u16* qb = q + ((size_t)bh * T_ + qt * 32) * D_;
    const u16* kb = k + (size_t)bh * T_ * D_;
    const u16* vb = vt + (size_t)bh * D_ * T_;   // [d][t]

    // Q as B-operand: lane n=q=lm, k=d=lq*8+j
    bf16x8 bq[2][2];
#pragma unroll
    for (int qt2 = 0; qt2 < 2; ++qt2) {
      const u16* qp = qb + (qt2 * 16 + lm) * D_ + lq * 8;
      bq[qt2][0] = *reinterpret_cast<const bf16x8*>(qp);
      bq[qt2][1] = *reinterpret_cast<const bf16x8*>(qp + 32);
    }

    f32x4 o[4][2];                 // O^T tiles: [d-tile][q-subtile]
#pragma unroll
    for (int dt = 0; dt < 4; ++dt)
#pragma unroll
      for (int qt2 = 0; qt2 < 2; ++qt2) o[dt][qt2] = (f32x4){0.f, 0.f, 0.f, 0.f};
    float mprev[2] = {-1e30f, -1e30f}, lsum[2] = {0.f, 0.f};

    const int klast = qt >> 1;

    for (int kbi = 0; kbi <= klast; ++kbi) {
      // K as A-operand: lane m=key=lm, k=d
      bf16x8 kf[4][2];
#pragma unroll
      for (int nt = 0; nt < 4; ++nt) {
        const u16* kp = kb + (size_t)(kbi * 64 + nt * 16 + lm) * D_ + lq * 8;
        kf[nt][0] = *reinterpret_cast<const bf16x8*>(kp);
        kf[nt][1] = *reinterpret_cast<const bf16x8*>(kp + 32);
      }
      // V^T as A-operand: lane m=d=lm(+16*dt), k=key
      bf16x8 vf[4][2];
#pragma unroll
      for (int dt = 0; dt < 4; ++dt) {
        const u16* vp = vb + (size_t)(dt * 16 + lm) * T_ + kbi * 64 + lq * 8;
        vf[dt][0] = *reinterpret_cast<const bf16x8*>(vp);
        vf[dt][1] = *reinterpret_cast<const bf16x8*>(vp + 32);
      }

      // S^T[key][q] (already in exp2 domain: q pre-scaled)
      f32x4 s[4][2];
#pragma unroll
      for (int kt = 0; kt < 4; ++kt)
#pragma unroll
        for (int qt2 = 0; qt2 < 2; ++qt2) {
          f32x4 z = (f32x4){0.f, 0.f, 0.f, 0.f};
          z = __builtin_amdgcn_mfma_f32_16x16x32_bf16(kf[kt][0], bq[qt2][0], z, 0, 0, 0);
          z = __builtin_amdgcn_mfma_f32_16x16x32_bf16(kf[kt][1], bq[qt2][1], z, 0, 0, 0);
          s[kt][qt2] = z;
        }

      bool maskt = (kbi == klast);
#pragma unroll
      for (int qt2 = 0; qt2 < 2; ++qt2) {
        int qg = qt * 32 + qt2 * 16 + lm;
        float mval = -1e30f;
        if (maskt) {
#pragma unroll
          for (int kt = 0; kt < 4; ++kt)
#pragma unroll
            for (int r = 0; r < 4; ++r) {
              int key = kbi * 64 + kt * 16 + lq * 4 + r;
              float sv = (key > qg) ? -1e30f : s[kt][qt2][r];
              s[kt][qt2][r] = sv;
              mval = fmaxf(mval, sv);
            }
        } else {
#pragma unroll
          for (int kt = 0; kt < 4; ++kt)
#pragma unroll
            for (int r = 0; r < 4; ++r) mval = fmaxf(mval, s[kt][qt2][r]);
        }
        mval = fmaxf(mval, __shfl_xor(mval, 16));
        mval = fmaxf(mval, __shfl_xor(mval, 32));
        float mold = mprev[qt2];
        float mnew = fmaxf(mold, mval);
        unsigned long long upd = __ballot(mval > mold);
        if (upd) {                       // wave-uniform branch
          float alpha = __builtin_exp2f(mold - mnew);
          lsum[qt2] *= alpha;
#pragma unroll
          for (int dt = 0; dt < 4; ++dt) o[dt][qt2] *= alpha;
          mprev[qt2] = mnew;
        }
        float rs = 0.f;
#pragma unroll
        for (int kt = 0; kt < 4; ++kt) {
          unsigned pu[4];
#pragma unroll
          for (int r = 0; r < 4; ++r) {
            float p = __builtin_exp2f(s[kt][qt2][r] - mnew);
            rs += p;
            union { float f; unsigned u; } cc; cc.f = p;
            pu[r] = cc.u;
          }
          // truncating bf16 pack: 2 keys/u32
          unsigned w0 = (pu[0] >> 16) | (pu[1] & 0xffff0000u);
          unsigned w1 = (pu[2] >> 16) | (pu[3] & 0xffff0000u);
          unsigned long long wv = ((unsigned long long)w1 << 32) | w0;
          *reinterpret_cast<unsigned long long*>(&Ps[qt2][lm][kt * 16 + lq * 4]) = wv;
        }
        rs += __shfl_xor(rs, 16);
        rs += __shfl_xor(rs, 32);
        lsum[qt2] += rs;
      }

      // PV: O^T += V^T P^T  (per-wave LDS readback, no barrier)
#pragma unroll
      for (int qt2 = 0; qt2 < 2; ++qt2) {
        bf16x8 p0 = *reinterpret_cast<const bf16x8*>(&Ps[qt2][lm][lq * 8]);
        bf16x8 p1 = *reinterpret_cast<const bf16x8*>(&Ps[qt2][lm][32 + lq * 8]);
#pragma unroll
        for (int dt = 0; dt < 4; ++dt) {
          o[dt][qt2] = __builtin_amdgcn_mfma_f32_16x16x32_bf16(vf[dt][0], p0, o[dt][qt2], 0, 0, 0);
          o[dt][qt2] = __builtin_amdgcn_mfma_f32_16x16x32_bf16(vf[dt][1], p1, o[dt][qt2], 0, 0, 0);
        }
      }
    }

    // write y[b][t=q][h][d]; O^T C-layout: col=q=lm, row=d=dt*16+lq*4+r -> 8B stores
#pragma unroll
    for (int qt2 = 0; qt2 < 2; ++qt2) {
      float inv = 1.f / lsum[qt2];
      int qg = qt * 32 + qt2 * 16 + lm;
#pragma unroll
      for (int dt = 0; dt < 4; ++dt) {
        u16 w[4];
#pragma unroll
        for (int r = 0; r < 4; ++r) w[r] = f2bf(o[dt][qt2][r] * inv);
        int d = dt * 16 + lq * 4;
        *reinterpret_cast<uint2*>(&y[((size_t)(b * T_ + qg) * NH_ + h) * D_ + d]) =
            *reinterpret_cast<uint2*>(w);
      }
    }

    // steal next item
    unsigned nv = 0;
    if (lane == 0) nv = atomicAdd(ctr, 1u);
    idx = __shfl((int)nv, 0);
  }
}

// ---------------- Proj GEMM: y[M,K] x WpT[N,K] + b_proj -> out fp32 ----------------
__global__ __launch_bounds__(256) void gemm_proj(const u16* __restrict__ A,
                                                 const u16* __restrict__ Bt,
                                                 const float* __restrict__ b_proj,
                                                 float* __restrict__ out) {
  const int K = C_, N = C_;
  int bm = blockIdx.y, bn = blockIdx.x;
  int tid = threadIdx.x;
  int wid = tid >> 6, lane = tid & 63;
  int lm = lane & 15, lq = lane >> 4;
  int wm = (wid >> 1) * 64, wn = (wid & 1) * 64;

  __shared__ u16 As[128][40];
  __shared__ u16 Bs[128][40];

  f32x4 acc[4][4];
#pragma unroll
  for (int i = 0; i < 4; ++i)
#pragma unroll
    for (int j = 0; j < 4; ++j) acc[i][j] = (f32x4){0.f, 0.f, 0.f, 0.f};

  const u16* Ab = A + (bm * 128) * K;
  const u16* Bb = Bt + (bn * 128) * K;
  int sr = tid >> 1;
  int sc = (tid & 1) * 16;

  for (int k0 = 0; k0 < K; k0 += 32) {
    ulonglong2 va0 = *reinterpret_cast<const ulonglong2*>(Ab + sr * K + k0 + sc);
    ulonglong2 va1 = *reinterpret_cast<const ulonglong2*>(Ab + sr * K + k0 + sc + 8);
    ulonglong2 vb0 = *reinterpret_cast<const ulonglong2*>(Bb + sr * K + k0 + sc);
    ulonglong2 vb1 = *reinterpret_cast<const ulonglong2*>(Bb + sr * K + k0 + sc + 8);
    __syncthreads();
    *reinterpret_cast<ulonglong2*>(&As[sr][sc]) = va0;
    *reinterpret_cast<ulonglong2*>(&As[sr][sc + 8]) = va1;
    *reinterpret_cast<ulonglong2*>(&Bs[sr][sc]) = vb0;
    *reinterpret_cast<ulonglong2*>(&Bs[sr][sc + 8]) = vb1;
    __syncthreads();
    bf16x8 af[4], bf[4];
#pragma unroll
    for (int mt = 0; mt < 4; ++mt)
      af[mt] = *reinterpret_cast<const bf16x8*>(&As[wm + mt * 16 + lm][lq * 8]);
#pragma unroll
    for (int nt = 0; nt < 4; ++nt)
      bf[nt] = *reinterpret_cast<const bf16x8*>(&Bs[wn + nt * 16 + lm][lq * 8]);
#pragma unroll
    for (int mt = 0; mt < 4; ++mt)
#pragma unroll
      for (int nt = 0; nt < 4; ++nt)
        acc[mt][nt] = __builtin_amdgcn_mfma_f32_16x16x32_bf16(af[mt], bf[nt], acc[mt][nt], 0, 0, 0);
  }

#pragma unroll
  for (int mt = 0; mt < 4; ++mt) {
#pragma unroll
    for (int nt = 0; nt < 4; ++nt) {
#pragma unroll
      for (int r = 0; r < 4; ++r) {
        int m = bm * 128 + wm + mt * 16 + lq * 4 + r;
        int n = bn * 128 + wn + nt * 16 + lm;
        out[m * N + n] = acc[mt][nt][r] + b_proj[n];
      }
    }
  }
}

extern "C" void kernel_launch(void* const* d_in, const int* in_sizes, int n_in,
                              void* d_out, int out_size, void* d_ws, size_t ws_size,
                              hipStream_t stream) {
  const float* x      = (const float*)d_in[0];
  const float* W_attn = (const float*)d_in[1];
  const float* b_attn = (const float*)d_in[2];
  const float* bQ     = (const float*)d_in[3];
  const float* bK     = (const float*)d_in[4];
  const float* W_proj = (const float*)d_in[5];
  const float* b_proj = (const float*)d_in[6];
  float* out = (float*)d_out;

  char* ws = (char*)d_ws;
  u16* xb  = (u16*)(ws);                              // [8192][1024]      16 MB
  u16* WaT = (u16*)(ws + 16777216);                   // [3072][1024]       6 MB
  u16* WpT = (u16*)(ws + 23068672);                   // [1024][1024]       2 MB
  u16* qw  = (u16*)(ws + 25165824);                   // [B,NH,T,D] scaled 16 MB
  u16* kw  = (u16*)(ws + 41943040);                   // [B,NH,T,D]        16 MB
  u16* vw  = (u16*)(ws + 58720256);                   // [B,NH,D,T] (V^T)  16 MB
  u16* yw  = (u16*)(ws + 75497472);                   // [8192][1024]      16 MB
  unsigned* ctr = (unsigned*)(ws + 92274688);         // work-steal counter

  conv_bf16<<<M_ * C_ / (4 * 256), 256, 0, stream>>>(x, xb, M_ * C_);
  {
    dim3 g(N_QKV / 32, C_ / 32);
    transpose_bf16<<<g, 256, 0, stream>>>(W_attn, WaT, C_, N_QKV);
  }
  {
    dim3 g(C_ / 32, C_ / 32);
    transpose_bf16<<<g, 256, 0, stream>>>(W_proj, WpT, C_, C_);
  }
  {
    dim3 g(N_QKV / 128, M_ / 128);  // (24, 64)
    gemm_qkv<<<g, 256, 0, stream>>>(xb, WaT, b_attn, bQ, bK, qw, kw, vw, ctr);
  }
  attn_kernel<<<ATTN_WAVES, 64, 0, stream>>>(qw, kw, vw, yw, ctr);
  {
    dim3 g(C_ / 128, M_ / 128);     // (8, 64)
    gemm_proj<<<g, 256, 0, stream>>>(yw, WpT, b_proj, out);
  }
}

// Round 5
// 366.902 us; speedup vs baseline: 1.5391x; 1.0936x over previous
//
#include <hip/hip_runtime.h>

typedef unsigned short u16;
typedef unsigned int u32;
typedef __bf16 bf16x8 __attribute__((ext_vector_type(8)));
typedef float f32x4 __attribute__((ext_vector_type(4)));

#define B_  4
#define T_  2048
#define C_  1024
#define NH_ 16
#define D_  64
#define M_  (B_*T_)          // 8192
#define N_QKV (3*C_)         // 3072

#define ATTN_WAVES 3072      // 12 per CU (3 per SIMD)
#define ATTN_ITEMS 4096      // 64 bh x 64 q-tiles of 32 rows

// async global->LDS, 16B per lane. LDS dest = wave-uniform base + lane*16
// (generic LDS ptr low 32 bits == LDS offset on gfx9+, so truncation == addrspacecast)
__device__ __forceinline__ void async_copy16(void* lds, const void* gptr) {
  __builtin_amdgcn_global_load_lds(
      (const __attribute__((address_space(1))) u32*)gptr,
      (__attribute__((address_space(3))) u32*)(u32)(uintptr_t)lds,
      16, 0, 0);
}

// RNE float -> bf16 bits
__device__ __forceinline__ u16 f2bf(float f) {
  union { float f; unsigned u; } c; c.f = f;
  unsigned u = c.u;
  unsigned r = (u + 0x7fffu + ((u >> 16) & 1u)) >> 16;
  return (u16)r;
}

// ---------------- elementwise fp32 -> bf16 ----------------
__global__ __launch_bounds__(256) void conv_bf16(const float* __restrict__ in,
                                                 u16* __restrict__ out, int n) {
  int i = (blockIdx.x * 256 + threadIdx.x) * 4;
  if (i < n) {
    float4 f = *reinterpret_cast<const float4*>(in + i);
    u16 o[4] = { f2bf(f.x), f2bf(f.y), f2bf(f.z), f2bf(f.w) };
    *reinterpret_cast<uint2*>(out + i) = *reinterpret_cast<uint2*>(o);
  }
}

// ---------------- transpose fp32 [K][N] -> bf16 [N][K] ----------------
__global__ __launch_bounds__(256) void transpose_bf16(const float* __restrict__ in,
                                                      u16* __restrict__ out,
                                                      int K, int N) {
  __shared__ float tile[32][33];
  int bi = blockIdx.y;           // K/32
  int bj = blockIdx.x;           // N/32
  int tx = threadIdx.x & 31;
  int ty = threadIdx.x >> 5;     // 0..7
#pragma unroll
  for (int i = 0; i < 4; ++i) {
    int row = ty + i * 8;
    tile[row][tx] = in[(bi * 32 + row) * N + bj * 32 + tx];
  }
  __syncthreads();
#pragma unroll
  for (int i = 0; i < 4; ++i) {
    int row = ty + i * 8;
    out[(bj * 32 + row) * K + bi * 32 + tx] = f2bf(tile[tx][row]);
  }
}

// ---------------- QKV GEMM (m97 structure): global_load_lds staging ----------------
// 128x128 tile, BK=32, As/Bs flat [128][32] u16 (NO padding - global_load_lds
// requires lane-contiguous LDS). q stored pre-scaled by 1/sqrt(D)*log2(e);
// k with bias; v transposed [b,h,d,t]. Also seeds the attention steal counter.
__global__ __launch_bounds__(256) void gemm_qkv(const u16* __restrict__ A,
                                                const u16* __restrict__ Bt,
                                                const float* __restrict__ b_attn,
                                                const float* __restrict__ bQ,
                                                const float* __restrict__ bK,
                                                u16* __restrict__ qo,
                                                u16* __restrict__ ko,
                                                u16* __restrict__ vo,
                                                unsigned* __restrict__ ctr) {
  const int K = C_;
  int bm = blockIdx.y, bn = blockIdx.x;
  int tid = threadIdx.x;
  if (tid == 0 && bm == 0 && bn == 0) *ctr = ATTN_WAVES;
  int wid = tid >> 6, lane = tid & 63;
  int lm = lane & 15, lq = lane >> 4;
  int wm = (wid >> 1) * 64, wn = (wid & 1) * 64;

  __shared__ u16 As[128 * 32];
  __shared__ u16 Bs[128 * 32];

  f32x4 acc[4][4];
#pragma unroll
  for (int i = 0; i < 4; ++i)
#pragma unroll
    for (int j = 0; j < 4; ++j) acc[i][j] = (f32x4){0.f, 0.f, 0.f, 0.f};

  const u16* Ab = A + (bm * 128) * K;
  const u16* Bb = Bt + (bn * 128) * K;
  // staging: chunk c (0..7) = rows 16c..16c+15 (64B/row); lane i -> byte c*1024+i*16
  int srow = lane >> 2;            // 0..15 within chunk
  int scol = (lane & 3) * 8;       // u16 col

  for (int k0 = 0; k0 < K; k0 += 32) {
    __syncthreads();               // protect previous iteration's ds_reads
#pragma unroll
    for (int j = 0; j < 2; ++j) {
      int c = wid * 2 + j;
      int row = c * 16 + srow;
      async_copy16(&As[c * 512], Ab + row * K + k0 + scol);
      async_copy16(&Bs[c * 512], Bb + row * K + k0 + scol);
    }
    __syncthreads();               // compiler drains vmcnt before barrier
    bf16x8 af[4], bf[4];
#pragma unroll
    for (int mt = 0; mt < 4; ++mt)
      af[mt] = *reinterpret_cast<const bf16x8*>(&As[(wm + mt * 16 + lm) * 32 + lq * 8]);
#pragma unroll
    for (int nt = 0; nt < 4; ++nt)
      bf[nt] = *reinterpret_cast<const bf16x8*>(&Bs[(wn + nt * 16 + lm) * 32 + lq * 8]);
#pragma unroll
    for (int mt = 0; mt < 4; ++mt)
#pragma unroll
      for (int nt = 0; nt < 4; ++nt)
        acc[mt][nt] = __builtin_amdgcn_mfma_f32_16x16x32_bf16(af[mt], bf[nt], acc[mt][nt], 0, 0, 0);
  }

  const float qscale = 0.18033688011112042f;  // 1/sqrt(64) * log2(e)
  // epilogue: C/D layout col=lane&15, row=(lane>>4)*4+reg  [verified m89/m91]
#pragma unroll
  for (int mt = 0; mt < 4; ++mt) {
#pragma unroll
    for (int nt = 0; nt < 4; ++nt) {
#pragma unroll
      for (int r = 0; r < 4; ++r) {
        int m = bm * 128 + wm + mt * 16 + lq * 4 + r;
        int n = bn * 128 + wn + nt * 16 + lm;
        float val = acc[mt][nt][r] + b_attn[n];
        int sel = n >> 10;
        int c = n & 1023;          // h*64+d
        int h = c >> 6;
        int d = c & 63;
        int b = m >> 11;
        int t = m & 2047;
        if (sel == 0)      qo[(((b * NH_ + h) * T_) + t) * D_ + d] = f2bf((val + bQ[c]) * qscale);
        else if (sel == 1) ko[(((b * NH_ + h) * T_) + t) * D_ + d] = f2bf(val + bK[c]);
        else               vo[(((b * NH_ + h) * D_) + d) * T_ + t] = f2bf(val);  // transposed
      }
    }
  }
}

// ---------------- Flash attention: persistent waves + work stealing ----------------
// 3072 single-wave blocks (12/CU). Work item idx in [0,4096): qt = 63-(idx>>6)
// (longest first), bh = idx&63. Wave does item blockIdx.x, then steals via *ctr.
// S^T = K Q^T formulation (q in lane dim): per-lane softmax state, 4 shfl/iter;
// P relayout via per-wave LDS, truncating bf16 pack.
__global__ __launch_bounds__(64) void attn_kernel(const u16* __restrict__ q,
                                                  const u16* __restrict__ k,
                                                  const u16* __restrict__ vt,
                                                  u16* __restrict__ y,
                                                  unsigned* __restrict__ ctr) {
  int lane = threadIdx.x;
  int lm = lane & 15, lq = lane >> 4;

  __shared__ u16 Ps[2][16][72];    // [q-subtile][q-row][local key], row stride 72

  int idx = blockIdx.x;
  while (idx < ATTN_ITEMS) {
    int qt = 63 - (idx >> 6);
    int bh = idx & 63;
    int b = bh >> 4, h = bh & 15;

    const u16* qb = q + ((size_t)bh * T_ + qt * 32) * D_;
    const u16* kb = k + (size_t)bh * T_ * D_;
    const u16* vb = vt + (size_t)bh * D_ * T_;   // [d][t]

    // Q as B-operand: lane n=q=lm, k=d=lq*8+j
    bf16x8 bq[2][2];
#pragma unroll
    for (int qt2 = 0; qt2 < 2; ++qt2) {
      const u16* qp = qb + (qt2 * 16 + lm) * D_ + lq * 8;
      bq[qt2][0] = *reinterpret_cast<const bf16x8*>(qp);
      bq[qt2][1] = *reinterpret_cast<const bf16x8*>(qp + 32);
    }

    f32x4 o[4][2];                 // O^T tiles: [d-tile][q-subtile]
#pragma unroll
    for (int dt = 0; dt < 4; ++dt)
#pragma unroll
      for (int qt2 = 0; qt2 < 2; ++qt2) o[dt][qt2] = (f32x4){0.f, 0.f, 0.f, 0.f};
    float mprev[2] = {-1e30f, -1e30f}, lsum[2] = {0.f, 0.f};

    const int klast = qt >> 1;

    for (int kbi = 0; kbi <= klast; ++kbi) {
      // K as A-operand: lane m=key=lm, k=d
      bf16x8 kf[4][2];
#pragma unroll
      for (int nt = 0; nt < 4; ++nt) {
        const u16* kp = kb + (size_t)(kbi * 64 + nt * 16 + lm) * D_ + lq * 8;
        kf[nt][0] = *reinterpret_cast<const bf16x8*>(kp);
        kf[nt][1] = *reinterpret_cast<const bf16x8*>(kp + 32);
      }
      // V^T as A-operand: lane m=d=lm(+16*dt), k=key
      bf16x8 vf[4][2];
#pragma unroll
      for (int dt = 0; dt < 4; ++dt) {
        const u16* vp = vb + (size_t)(dt * 16 + lm) * T_ + kbi * 64 + lq * 8;
        vf[dt][0] = *reinterpret_cast<const bf16x8*>(vp);
        vf[dt][1] = *reinterpret_cast<const bf16x8*>(vp + 32);
      }

      // S^T[key][q] (already in exp2 domain: q pre-scaled)
      f32x4 s[4][2];
#pragma unroll
      for (int kt = 0; kt < 4; ++kt)
#pragma unroll
        for (int qt2 = 0; qt2 < 2; ++qt2) {
          f32x4 z = (f32x4){0.f, 0.f, 0.f, 0.f};
          z = __builtin_amdgcn_mfma_f32_16x16x32_bf16(kf[kt][0], bq[qt2][0], z, 0, 0, 0);
          z = __builtin_amdgcn_mfma_f32_16x16x32_bf16(kf[kt][1], bq[qt2][1], z, 0, 0, 0);
          s[kt][qt2] = z;
        }

      bool maskt = (kbi == klast);
#pragma unroll
      for (int qt2 = 0; qt2 < 2; ++qt2) {
        int qg = qt * 32 + qt2 * 16 + lm;
        float mval = -1e30f;
        if (maskt) {
#pragma unroll
          for (int kt = 0; kt < 4; ++kt)
#pragma unroll
            for (int r = 0; r < 4; ++r) {
              int key = kbi * 64 + kt * 16 + lq * 4 + r;
              float sv = (key > qg) ? -1e30f : s[kt][qt2][r];
              s[kt][qt2][r] = sv;
              mval = fmaxf(mval, sv);
            }
        } else {
#pragma unroll
          for (int kt = 0; kt < 4; ++kt)
#pragma unroll
            for (int r = 0; r < 4; ++r) mval = fmaxf(mval, s[kt][qt2][r]);
        }
        mval = fmaxf(mval, __shfl_xor(mval, 16));
        mval = fmaxf(mval, __shfl_xor(mval, 32));
        float mold = mprev[qt2];
        float mnew = fmaxf(mold, mval);
        unsigned long long upd = __ballot(mval > mold);
        if (upd) {                       // wave-uniform branch
          float alpha = __builtin_exp2f(mold - mnew);
          lsum[qt2] *= alpha;
#pragma unroll
          for (int dt = 0; dt < 4; ++dt) o[dt][qt2] *= alpha;
          mprev[qt2] = mnew;
        }
        float rs = 0.f;
#pragma unroll
        for (int kt = 0; kt < 4; ++kt) {
          unsigned pu[4];
#pragma unroll
          for (int r = 0; r < 4; ++r) {
            float p = __builtin_exp2f(s[kt][qt2][r] - mnew);
            rs += p;
            union { float f; unsigned u; } cc; cc.f = p;
            pu[r] = cc.u;
          }
          // truncating bf16 pack: 2 keys/u32
          unsigned w0 = (pu[0] >> 16) | (pu[1] & 0xffff0000u);
          unsigned w1 = (pu[2] >> 16) | (pu[3] & 0xffff0000u);
          unsigned long long wv = ((unsigned long long)w1 << 32) | w0;
          *reinterpret_cast<unsigned long long*>(&Ps[qt2][lm][kt * 16 + lq * 4]) = wv;
        }
        rs += __shfl_xor(rs, 16);
        rs += __shfl_xor(rs, 32);
        lsum[qt2] += rs;
      }

      // PV: O^T += V^T P^T  (per-wave LDS readback, no barrier)
#pragma unroll
      for (int qt2 = 0; qt2 < 2; ++qt2) {
        bf16x8 p0 = *reinterpret_cast<const bf16x8*>(&Ps[qt2][lm][lq * 8]);
        bf16x8 p1 = *reinterpret_cast<const bf16x8*>(&Ps[qt2][lm][32 + lq * 8]);
#pragma unroll
        for (int dt = 0; dt < 4; ++dt) {
          o[dt][qt2] = __builtin_amdgcn_mfma_f32_16x16x32_bf16(vf[dt][0], p0, o[dt][qt2], 0, 0, 0);
          o[dt][qt2] = __builtin_amdgcn_mfma_f32_16x16x32_bf16(vf[dt][1], p1, o[dt][qt2], 0, 0, 0);
        }
      }
    }

    // write y[b][t=q][h][d]; O^T C-layout: col=q=lm, row=d=dt*16+lq*4+r -> 8B stores
#pragma unroll
    for (int qt2 = 0; qt2 < 2; ++qt2) {
      float inv = 1.f / lsum[qt2];
      int qg = qt * 32 + qt2 * 16 + lm;
#pragma unroll
      for (int dt = 0; dt < 4; ++dt) {
        u16 w[4];
#pragma unroll
        for (int r = 0; r < 4; ++r) w[r] = f2bf(o[dt][qt2][r] * inv);
        int d = dt * 16 + lq * 4;
        *reinterpret_cast<uint2*>(&y[((size_t)(b * T_ + qg) * NH_ + h) * D_ + d]) =
            *reinterpret_cast<uint2*>(w);
      }
    }

    // steal next item
    unsigned nv = 0;
    if (lane == 0) nv = atomicAdd(ctr, 1u);
    idx = __shfl((int)nv, 0);
  }
}

// ---------------- Proj GEMM (m97 structure): y[M,K] x WpT[N,K] + b_proj -> fp32 ----------------
__global__ __launch_bounds__(256) void gemm_proj(const u16* __restrict__ A,
                                                 const u16* __restrict__ Bt,
                                                 const float* __restrict__ b_proj,
                                                 float* __restrict__ out) {
  const int K = C_, N = C_;
  int bm = blockIdx.y, bn = blockIdx.x;
  int tid = threadIdx.x;
  int wid = tid >> 6, lane = tid & 63;
  int lm = lane & 15, lq = lane >> 4;
  int wm = (wid >> 1) * 64, wn = (wid & 1) * 64;

  __shared__ u16 As[128 * 32];
  __shared__ u16 Bs[128 * 32];

  f32x4 acc[4][4];
#pragma unroll
  for (int i = 0; i < 4; ++i)
#pragma unroll
    for (int j = 0; j < 4; ++j) acc[i][j] = (f32x4){0.f, 0.f, 0.f, 0.f};

  const u16* Ab = A + (bm * 128) * K;
  const u16* Bb = Bt + (bn * 128) * K;
  int srow = lane >> 2;
  int scol = (lane & 3) * 8;

  for (int k0 = 0; k0 < K; k0 += 32) {
    __syncthreads();
#pragma unroll
    for (int j = 0; j < 2; ++j) {
      int c = wid * 2 + j;
      int row = c * 16 + srow;
      async_copy16(&As[c * 512], Ab + row * K + k0 + scol);
      async_copy16(&Bs[c * 512], Bb + row * K + k0 + scol);
    }
    __syncthreads();
    bf16x8 af[4], bf[4];
#pragma unroll
    for (int mt = 0; mt < 4; ++mt)
      af[mt] = *reinterpret_cast<const bf16x8*>(&As[(wm + mt * 16 + lm) * 32 + lq * 8]);
#pragma unroll
    for (int nt = 0; nt < 4; ++nt)
      bf[nt] = *reinterpret_cast<const bf16x8*>(&Bs[(wn + nt * 16 + lm) * 32 + lq * 8]);
#pragma unroll
    for (int mt = 0; mt < 4; ++mt)
#pragma unroll
      for (int nt = 0; nt < 4; ++nt)
        acc[mt][nt] = __builtin_amdgcn_mfma_f32_16x16x32_bf16(af[mt], bf[nt], acc[mt][nt], 0, 0, 0);
  }

#pragma unroll
  for (int mt = 0; mt < 4; ++mt) {
#pragma unroll
    for (int nt = 0; nt < 4; ++nt) {
#pragma unroll
      for (int r = 0; r < 4; ++r) {
        int m = bm * 128 + wm + mt * 16 + lq * 4 + r;
        int n = bn * 128 + wn + nt * 16 + lm;
        out[m * N + n] = acc[mt][nt][r] + b_proj[n];
      }
    }
  }
}

extern "C" void kernel_launch(void* const* d_in, const int* in_sizes, int n_in,
                              void* d_out, int out_size, void* d_ws, size_t ws_size,
                              hipStream_t stream) {
  const float* x      = (const float*)d_in[0];
  const float* W_attn = (const float*)d_in[1];
  const float* b_attn = (const float*)d_in[2];
  const float* bQ     = (const float*)d_in[3];
  const float* bK     = (const float*)d_in[4];
  const float* W_proj = (const float*)d_in[5];
  const float* b_proj = (const float*)d_in[6];
  float* out = (float*)d_out;

  char* ws = (char*)d_ws;
  u16* xb  = (u16*)(ws);                              // [8192][1024]      16 MB
  u16* WaT = (u16*)(ws + 16777216);                   // [3072][1024]       6 MB
  u16* WpT = (u16*)(ws + 23068672);                   // [1024][1024]       2 MB
  u16* qw  = (u16*)(ws + 25165824);                   // [B,NH,T,D] scaled 16 MB
  u16* kw  = (u16*)(ws + 41943040);                   // [B,NH,T,D]        16 MB
  u16* vw  = (u16*)(ws + 58720256);                   // [B,NH,D,T] (V^T)  16 MB
  u16* yw  = (u16*)(ws + 75497472);                   // [8192][1024]      16 MB
  unsigned* ctr = (unsigned*)(ws + 92274688);         // work-steal counter

  conv_bf16<<<M_ * C_ / (4 * 256), 256, 0, stream>>>(x, xb, M_ * C_);
  {
    dim3 g(N_QKV / 32, C_ / 32);
    transpose_bf16<<<g, 256, 0, stream>>>(W_attn, WaT, C_, N_QKV);
  }
  {
    dim3 g(C_ / 32, C_ / 32);
    transpose_bf16<<<g, 256, 0, stream>>>(W_proj, WpT, C_, C_);
  }
  {
    dim3 g(N_QKV / 128, M_ / 128);  // (24, 64)
    gemm_qkv<<<g, 256, 0, stream>>>(xb, WaT, b_attn, bQ, bK, qw, kw, vw, ctr);
  }
  attn_kernel<<<ATTN_WAVES, 64, 0, stream>>>(qw, kw, vw, yw, ctr);
  {
    dim3 g(C_ / 128, M_ / 128);     // (8, 64)
    gemm_proj<<<g, 256, 0, stream>>>(yw, WpT, b_proj, out);
  }
}